// Round 17
// baseline (349.686 us; speedup 1.0000x reference)
//
#include <hip/hip_runtime.h>
#include <stdint.h>

#define E_N 600000
#define N_N 100000
#define UNITS 4

typedef short short8   __attribute__((ext_vector_type(8)));
typedef short short8a  __attribute__((ext_vector_type(8), may_alias));
typedef float floatx2  __attribute__((ext_vector_type(2)));
typedef float floatx4  __attribute__((ext_vector_type(4)));
typedef float floatx16 __attribute__((ext_vector_type(16)));
typedef float floatx4a __attribute__((ext_vector_type(4), may_alias));
typedef float floatx8a __attribute__((ext_vector_type(8), may_alias));
typedef unsigned int uintx2  __attribute__((ext_vector_type(2)));
typedef unsigned int uintx4  __attribute__((ext_vector_type(4)));
typedef unsigned int uintx4a __attribute__((ext_vector_type(4), may_alias));
typedef __bf16 bf16x4 __attribute__((ext_vector_type(4)));
typedef __bf16 bf16x8 __attribute__((ext_vector_type(8)));

static __device__ __forceinline__ unsigned short f2bf(float f){
  unsigned u = __builtin_bit_cast(unsigned, f);
  unsigned rnd = 0x7fffu + ((u >> 16) & 1u);
  return (unsigned short)((u + rnd) >> 16);
}
static __device__ __forceinline__ unsigned pk2(float a, float b){
  floatx2 f; f[0] = a; f[1] = b;
  typedef __bf16 bf16x2 __attribute__((ext_vector_type(2)));
  return __builtin_bit_cast(unsigned, __builtin_convertvector(f, bf16x2));
}

// counted-vmcnt phase boundary (drains gld_lds staging; register loads are
// compiler-tracked). memory clobbers pin instruction placement across it.
#define WAITBAR(N) do{ \
  asm volatile("s_waitcnt vmcnt(" #N ")" ::: "memory"); \
  __builtin_amdgcn_s_barrier(); \
  asm volatile("" ::: "memory"); }while(0)
#define ORDER() asm volatile("" ::: "memory")

// ---- prep: weights -> bf16, EIGHT 16KB windows (k=64 each; 128 chans x 32 dw):
// wins 0..5 = W1 (k 0..383), wins 6..7 = W2 (k 0..127).
// u16 index: win*8192 + (c*32 + ((kp>>1) ^ ((c&7)<<2)))*2 + (kp&1)
__global__ void prep_weights(const float* __restrict__ W1, const float* __restrict__ W2,
                             unsigned short* __restrict__ wall){
  int i = blockIdx.x * 256 + threadIdx.x;
  int c, k, win; float v;
  if (i < 384 * 128){
    c = i / 384; k = i - c * 384; win = k >> 6;
    v = W1[k * 128 + c];
  } else {
    int j = i - 384 * 128;            // grid exact: j < 16384
    c = j >> 7; k = j & 127; win = 6 + (k >> 6);
    v = W2[k * 128 + c];
  }
  int kp = k & 63;
  wall[win * 8192 + (c * 32 + ((kp >> 1) ^ ((c & 7) << 2))) * 2 + (kp & 1)] = f2bf(v);
}

// ---- prep: copy nfeat -> output[1]; nfeat f32 -> bf16 in ws
__global__ void prep_nfeat(const float* __restrict__ nf,
                           unsigned* __restrict__ nfbu,
                           float* __restrict__ out2){
  const int total = N_N * 128 / 4;
  int stride = gridDim.x * blockDim.x;
  for (int i = blockIdx.x * blockDim.x + threadIdx.x; i < total; i += stride){
    float4 v = reinterpret_cast<const float4*>(nf)[i];
    reinterpret_cast<float4*>(out2)[i] = v;
    nfbu[2 * i]     = pk2(v.x, v.y);
    nfbu[2 * i + 1] = pk2(v.z, v.w);
  }
}

static __device__ __forceinline__ void glds16(void* lds, const void* g){
  __builtin_amdgcn_global_load_lds((const __attribute__((address_space(1))) unsigned int*)g,
                                   (__attribute__((address_space(3))) unsigned int*)lds,
                                   16, 0, 0);
}

// ---- fused, 32x32x16, operand-swapped, CROSS-UNIT software pipeline:
// 256 thr = 4 waves x 32 edges x 4 units (512 edges/block). 3-buffer window
// ring runs continuously across units (never drains). K-phase order per unit:
// src(P0,P1) -> dst(P2,P3) -> efeat(P4,P5) -> W2(P6,P7) -> epilogue, so
// next-unit gathers issue at P6/P7, next-unit efeat refills xe inside the
// epilogue, next-unit indices load at P0. Regs ~156 unified -> (256,3), no spill.
__global__ __launch_bounds__(256, 3) void fused_edge(
    const float* __restrict__ efeat,
    const int* __restrict__ src_idx, const int* __restrict__ dst_idx,
    const unsigned short* __restrict__ nfb,
    const unsigned short* __restrict__ wall,
    const float* __restrict__ b1, const float* __restrict__ b2,
    const float* __restrict__ lns, const float* __restrict__ lnb,
    float* __restrict__ out)
{
  // [0, 49152)      : three 16KB W buffers (ring)
  // [49152, 51200)  : biases: b1 | b2 | ln_scale | ln_bias (128 f32 each)
  __shared__ __align__(16) unsigned char smem[51200];
  unsigned int* wbuf  = (unsigned int*)smem;
  float*        cmisc = (float*)(smem + 49152);

  const int tid  = threadIdx.x;
  const int w    = tid >> 6;
  const int lane = tid & 63;
  const int rl   = lane & 31;     // A row (chan) / B col (edge) / D col (edge)
  const int hi   = lane >> 5;     // k-half; D row-offset 4*hi
  const int swz  = (rl & 7) << 2; // dword XOR swizzle (b128-aligned)

  auto stageW = [&](int b, int win){
    const unsigned char* src = (const unsigned char*)wall + win * 16384;
    #pragma unroll
    for (int rnd = 0; rnd < 4; ++rnd){
      int off = rnd * 4096 + tid * 16;
      glds16(smem + b * 16384 + off, src + off);
    }
  };
  auto ldE = [&](int e, int ks8) -> short8 {
    floatx8a f = *reinterpret_cast<const floatx8a*>(efeat + (size_t)e * 128 + ks8 * 16 + hi * 8);
    return __builtin_bit_cast(short8, __builtin_convertvector(f, bf16x8));
  };

  short8 xe[8], ga[4], gb[4];
  auto gather4 = [&](short8* dst, int row, int k0){
    #pragma unroll
    for (int k = 0; k < 4; ++k)
      dst[k] = *reinterpret_cast<const short8a*>(nfb + (size_t)row * 128 + (k0 + k) * 16 + hi * 8);
  };
  auto loadW = [&](const unsigned int* base, int m, int ks) -> short8 {
    uintx4a v = *reinterpret_cast<const uintx4a*>(
        &base[(32 * m + rl) * 32 + ((ks * 8 + hi * 4) ^ swz)]);
    return __builtin_bit_cast(short8, v);
  };

  // ---- prologue: windows w2,w3 (src segment), biases, unit-0 operands
  stageW(0, 2);
  stageW(1, 3);
  cmisc[tid]       = tid < 128 ? b1[tid]  : b2[tid - 128];
  cmisc[tid + 256] = tid < 128 ? lns[tid] : lnb[tid - 128];
  ORDER();

  const int ebase = blockIdx.x * (UNITS * 128);
  {
    int e  = ebase + w * 32 + rl;
    int ec = e < E_N ? e : (E_N - 1);
    int s0 = src_idx[ec];
    int d0 = dst_idx[ec];
    s0 = s0 < 0 ? 0 : (s0 >= N_N ? N_N - 1 : s0);
    d0 = d0 < 0 ? 0 : (d0 >= N_N ? N_N - 1 : d0);
    gather4(ga, s0, 0);
    gather4(gb, s0, 4);
    #pragma unroll
    for (int k = 0; k < 8; ++k) xe[k] = ldE(ec, k);
    // stash current-unit dst index in di
    ga[0] = ga[0]; // no-op
    // di variable:
    (void)0;
    // fallthrough to loop with di = d0
    // (declared below)
    asm volatile("s_waitcnt lgkmcnt(0)" ::: "memory");  // cmisc visible at barrier
    int di = d0;
    int sin = 0, din = 0;
    int cb = 0, sb = 2;

    #pragma unroll 1
    for (int u = 0; u < UNITS; ++u){
      const int e0  = ebase + u * 128 + w * 32 + rl;
      int en = ebase + (u + 1) * 128 + w * 32 + rl;
      const int ecn = en < E_N ? en : (E_N - 1);

      floatx16 acc1[4];
      #pragma unroll
      for (int mt = 0; mt < 4; ++mt)
        #pragma unroll
        for (int q = 0; q < 16; ++q) acc1[mt][q] = 0.f;

      auto g1 = [&](const unsigned int* B, const short8* xs){
        __builtin_amdgcn_s_setprio(1);
        #pragma unroll
        for (int ks = 0; ks < 4; ++ks)
          #pragma unroll
          for (int mt = 0; mt < 4; ++mt)
            acc1[mt] = __builtin_amdgcn_mfma_f32_32x32x16_bf16(loadW(B, mt, ks), xs[ks], acc1[mt], 0, 0, 0);
        __builtin_amdgcn_s_setprio(0);
      };

      // P0: consume w2 (src-lo, ga); stage w4; load next-unit indices
      WAITBAR(28);
      stageW(sb, 4); sb = sb == 2 ? 0 : sb + 1;
      sin = src_idx[ecn]; din = dst_idx[ecn];
      sin = sin < 0 ? 0 : (sin >= N_N ? N_N - 1 : sin);
      din = din < 0 ? 0 : (din >= N_N ? N_N - 1 : din);
      g1(wbuf + cb * 4096, ga); cb = cb == 2 ? 0 : cb + 1;

      // P1: consume w3 (src-hi, gb); stage w5; gather dst (this unit)
      WAITBAR(26);
      stageW(sb, 5); sb = sb == 2 ? 0 : sb + 1;
      g1(wbuf + cb * 4096, gb); cb = cb == 2 ? 0 : cb + 1;
      gather4(ga, di, 0);
      gather4(gb, di, 4);

      // P2: consume w4 (dst-lo, ga); stage w0
      WAITBAR(14);
      stageW(sb, 0); sb = sb == 2 ? 0 : sb + 1;
      g1(wbuf + cb * 4096, ga); cb = cb == 2 ? 0 : cb + 1;

      // P3: consume w5 (dst-hi, gb); stage w1
      WAITBAR(12);
      stageW(sb, 1); sb = sb == 2 ? 0 : sb + 1;
      g1(wbuf + cb * 4096, gb); cb = cb == 2 ? 0 : cb + 1;

      // P4: consume w0 (ef-lo, xe[0..3]); stage w6
      WAITBAR(4);
      stageW(sb, 6); sb = sb == 2 ? 0 : sb + 1;
      g1(wbuf + cb * 4096, xe); cb = cb == 2 ? 0 : cb + 1;

      // P5: consume w1 (ef-hi, xe[4..7]); stage w7
      WAITBAR(4);
      stageW(sb, 7); sb = sb == 2 ? 0 : sb + 1;
      g1(wbuf + cb * 4096, xe + 4); cb = cb == 2 ? 0 : cb + 1;

      // h-frag build in registers: silu(acc1+b1) -> bf16 -> lane<->lane+32
      short8 hfr[8];
      #pragma unroll
      for (int mt = 0; mt < 4; ++mt){
        floatx4 sv[4];
        #pragma unroll
        for (int p = 0; p < 4; ++p){
          floatx4 bb = *reinterpret_cast<const floatx4a*>(&cmisc[32 * mt + 8 * p + 4 * hi]);
          #pragma unroll
          for (int i = 0; i < 4; ++i){
            float xx = acc1[mt][4 * p + i] + bb[i];
            sv[p][i] = xx * __builtin_amdgcn_rcpf(1.f + __expf(-xx));   // silu
          }
        }
        #pragma unroll
        for (int k1 = 0; k1 < 2; ++k1){
          uintx2 P0v = __builtin_bit_cast(uintx2, __builtin_convertvector(sv[2 * k1],     bf16x4));
          uintx2 P1v = __builtin_bit_cast(uintx2, __builtin_convertvector(sv[2 * k1 + 1], bf16x4));
          unsigned sA = hi ? P0v[0] : P1v[0];
          unsigned sB = hi ? P0v[1] : P1v[1];
          unsigned rA = __shfl_xor(sA, 32);
          unsigned rB = __shfl_xor(sB, 32);
          uintx4 uu;
          uu[0] = hi ? rA : P0v[0];
          uu[1] = hi ? rB : P0v[1];
          uu[2] = hi ? P1v[0] : rA;
          uu[3] = hi ? P1v[1] : rB;
          hfr[2 * mt + k1] = __builtin_bit_cast(short8, uu);
        }
      }

      floatx16 acc2[4];
      #pragma unroll
      for (int mo = 0; mo < 4; ++mo)
        #pragma unroll
        for (int q = 0; q < 16; ++q) acc2[mo][q] = 0.f;

      // P6: consume w6 (W2-lo, hfr[0..3]); stage NEXT unit's w2; gather next src-lo
      WAITBAR(4);
      stageW(sb, 2); sb = sb == 2 ? 0 : sb + 1;
      __builtin_amdgcn_s_setprio(1);
      #pragma unroll
      for (int ks = 0; ks < 4; ++ks)
        #pragma unroll
        for (int mo = 0; mo < 4; ++mo)
          acc2[mo] = __builtin_amdgcn_mfma_f32_32x32x16_bf16(loadW(wbuf + cb * 4096, mo, ks), hfr[ks], acc2[mo], 0, 0, 0);
      __builtin_amdgcn_s_setprio(0);
      cb = cb == 2 ? 0 : cb + 1;
      gather4(ga, sin, 0);

      // P7: consume w7 (W2-hi, hfr[4..7]); stage next w3; gather next src-hi
      WAITBAR(8);
      stageW(sb, 3); sb = sb == 2 ? 0 : sb + 1;
      __builtin_amdgcn_s_setprio(1);
      #pragma unroll
      for (int ks = 0; ks < 4; ++ks)
        #pragma unroll
        for (int mo = 0; mo < 4; ++mo)
          acc2[mo] = __builtin_amdgcn_mfma_f32_32x32x16_bf16(loadW(wbuf + cb * 4096, mo, ks), hfr[4 + ks], acc2[mo], 0, 0, 0);
      __builtin_amdgcn_s_setprio(0);
      cb = cb == 2 ? 0 : cb + 1;
      gather4(gb, sin, 4);

      // ---- epilogue: LN + inline residual exchange + stores; refill xe (next)
      ORDER();
      float s1 = 0.f, s2 = 0.f;
      #pragma unroll
      for (int mt = 0; mt < 4; ++mt)
        #pragma unroll
        for (int p = 0; p < 4; ++p){
          floatx4 bb = *reinterpret_cast<const floatx4a*>(&cmisc[128 + 32 * mt + 8 * p + 4 * hi]);
          #pragma unroll
          for (int i = 0; i < 4; ++i){
            float v = acc2[mt][4 * p + i] + bb[i];
            s1 += v; s2 += v * v;
          }
        }
      s1 += __shfl_xor(s1, 32); s2 += __shfl_xor(s2, 32);

      float mu   = s1 * (1.f / 128.f);
      float var  = s2 * (1.f / 128.f) - mu * mu;
      var = var > 0.f ? var : 0.f;
      float rstd = __builtin_amdgcn_rsqf(var + 1e-5f);

      if (e0 < E_N){
        float* op = out + (size_t)e0 * 128;
        #pragma unroll
        for (int mt = 0; mt < 4; ++mt){
          #pragma unroll
          for (int hf = 0; hf < 2; ++hf){
            const int ks = 2 * mt + hf;
            uintx4 uu = __builtin_bit_cast(uintx4, xe[ks]);
            unsigned sA = hi ? uu[0] : uu[2];
            unsigned sB = hi ? uu[1] : uu[3];
            unsigned rA = __shfl_xor(sA, 32);
            unsigned rB = __shfl_xor(sB, 32);
            unsigned oA = hi ? uu[2] : uu[0];
            unsigned oB = hi ? uu[3] : uu[1];
            #pragma unroll
            for (int pp = 0; pp < 2; ++pp){
              const int p = 2 * hf + pp;
              int c = 32 * mt + 8 * p + 4 * hi;
              floatx4 bb = *reinterpret_cast<const floatx4a*>(&cmisc[128 + c]);
              floatx4 ls = *reinterpret_cast<const floatx4a*>(&cmisc[256 + c]);
              floatx4 lb = *reinterpret_cast<const floatx4a*>(&cmisc[384 + c]);
              unsigned d0 = ((p & 1) == hi) ? oA : rA;
              unsigned d1 = ((p & 1) == hi) ? oB : rB;
              floatx4 o4;
              #pragma unroll
              for (int i = 0; i < 4; ++i){
                unsigned dwv = (i >> 1) ? d1 : d0;
                float ef = __builtin_bit_cast(float, (i & 1) ? (dwv & 0xffff0000u) : (dwv << 16));
                o4[i] = (acc2[mt][4 * p + i] + bb[i] - mu) * rstd * ls[i] + lb[i] + ef;
              }
              *reinterpret_cast<floatx4a*>(op + c) = o4;
            }
          }
        }
      }

      // refill xe with next unit's efeat (all lanes, clamped) + advance dst idx
      #pragma unroll
      for (int k = 0; k < 8; ++k) xe[k] = ldE(ecn, k);
      di = din;
    }
  }
}

extern "C" void kernel_launch(void* const* d_in, const int* in_sizes, int n_in,
                              void* d_out, int out_size, void* d_ws, size_t ws_size,
                              hipStream_t stream){
  const float* efeat = (const float*)d_in[0];
  const float* nfeat = (const float*)d_in[1];
  const int*   srci  = (const int*)d_in[2];
  const int*   dsti  = (const int*)d_in[3];
  const float* W1    = (const float*)d_in[4];
  const float* b1    = (const float*)d_in[5];
  const float* W2    = (const float*)d_in[6];
  const float* b2    = (const float*)d_in[7];
  const float* lns   = (const float*)d_in[8];
  const float* lnb   = (const float*)d_in[9];
  float* out = (float*)d_out;

  char* ws = (char*)d_ws;
  unsigned short* wall = (unsigned short*)ws;              // 131,072 B (8 swizzled windows)
  unsigned short* nfb  = (unsigned short*)(ws + 131072);   // 25,600,000 B

  prep_weights<<<(384 * 128 + 128 * 128) / 256, 256, 0, stream>>>(W1, W2, wall);
  prep_nfeat<<<2048, 256, 0, stream>>>(nfeat, (unsigned*)nfb, out + (size_t)E_N * 128);

  int blocks = (E_N + UNITS * 128 - 1) / (UNITS * 128);   // 1172
  fused_edge<<<blocks, 256, 0, stream>>>(efeat, srci, dsti, nfb, wall,
                                         b1, b2, lns, lnb, out);
}

// Round 18
// 217.922 us; speedup vs baseline: 1.6046x; 1.6046x over previous
//
#include <hip/hip_runtime.h>
#include <stdint.h>

#define E_N 600000
#define N_N 100000

typedef short short8   __attribute__((ext_vector_type(8)));
typedef short short8a  __attribute__((ext_vector_type(8), may_alias));
typedef float floatx2  __attribute__((ext_vector_type(2)));
typedef float floatx4  __attribute__((ext_vector_type(4)));
typedef float floatx16 __attribute__((ext_vector_type(16)));
typedef float floatx4a __attribute__((ext_vector_type(4), may_alias));
typedef float floatx8a __attribute__((ext_vector_type(8), may_alias));
typedef unsigned int uintx2  __attribute__((ext_vector_type(2)));
typedef unsigned int uintx4  __attribute__((ext_vector_type(4)));
typedef unsigned int uintx4a __attribute__((ext_vector_type(4), may_alias));
typedef __bf16 bf16x4 __attribute__((ext_vector_type(4)));
typedef __bf16 bf16x8 __attribute__((ext_vector_type(8)));

static __device__ __forceinline__ unsigned short f2bf(float f){
  unsigned u = __builtin_bit_cast(unsigned, f);
  unsigned rnd = 0x7fffu + ((u >> 16) & 1u);
  return (unsigned short)((u + rnd) >> 16);
}
static __device__ __forceinline__ unsigned pk2(float a, float b){
  floatx2 f; f[0] = a; f[1] = b;
  typedef __bf16 bf16x2 __attribute__((ext_vector_type(2)));
  return __builtin_bit_cast(unsigned, __builtin_convertvector(f, bf16x2));
}

// counted-vmcnt phase boundary: wait for all loads except the last N, then
// raw barrier; memory-clobber asm on both sides pins LDS reads/loads in place.
#define WAITBAR(N) do{ \
  asm volatile("s_waitcnt vmcnt(" #N ")" ::: "memory"); \
  __builtin_amdgcn_s_barrier(); \
  asm volatile("" ::: "memory"); }while(0)
#define BARONLY() do{ \
  asm volatile("" ::: "memory"); \
  __builtin_amdgcn_s_barrier(); \
  asm volatile("" ::: "memory"); }while(0)

// ---- prep: weights -> bf16, EIGHT 16KB windows (k=64 each; rows=128 chans, 32 dw):
// wins 0..5 = W1 (k 0..383), wins 6..7 = W2 (k 0..127).
// u16 index: win*8192 + (c*32 + ((kp>>1) ^ ((c&7)<<2)))*2 + (kp&1)
__global__ void prep_weights(const float* __restrict__ W1, const float* __restrict__ W2,
                             unsigned short* __restrict__ wall){
  int i = blockIdx.x * 256 + threadIdx.x;
  int c, k, win; float v;
  if (i < 384 * 128){
    c = i / 384; k = i - c * 384; win = k >> 6;
    v = W1[k * 128 + c];
  } else {
    int j = i - 384 * 128;            // grid exact: j < 16384
    c = j >> 7; k = j & 127; win = 6 + (k >> 6);
    v = W2[k * 128 + c];
  }
  int kp = k & 63;
  wall[win * 8192 + (c * 32 + ((kp >> 1) ^ ((c & 7) << 2))) * 2 + (kp & 1)] = f2bf(v);
}

// ---- prep: copy nfeat -> output[1]; nfeat f32 -> bf16 in ws
__global__ void prep_nfeat(const float* __restrict__ nf,
                           unsigned* __restrict__ nfbu,
                           float* __restrict__ out2){
  const int total = N_N * 128 / 4;
  int stride = gridDim.x * blockDim.x;
  for (int i = blockIdx.x * blockDim.x + threadIdx.x; i < total; i += stride){
    float4 v = reinterpret_cast<const float4*>(nf)[i];
    reinterpret_cast<float4*>(out2)[i] = v;
    nfbu[2 * i]     = pk2(v.x, v.y);
    nfbu[2 * i + 1] = pk2(v.z, v.w);
  }
}

static __device__ __forceinline__ void glds16(void* lds, const void* g){
  __builtin_amdgcn_global_load_lds((const __attribute__((address_space(1))) unsigned int*)g,
                                   (__attribute__((address_space(3))) unsigned int*)lds,
                                   16, 0, 0);
}

// ---- fused, 32x32x16 MFMA, operand-swapped, COUNTED-VMCNT pipeline:
// 256 thr = 4 waves x 32 edges. THREE 16KB W buffers; stages and gathers are
// issued 2 windows ahead and stay in flight across barriers (vmcnt(8)/(4),
// never 0 mid-loop). In-register GEMM1->GEMM2 handoff + residual (r13).
__global__ __launch_bounds__(256, 3) void fused_edge(
    const float* __restrict__ efeat,
    const int* __restrict__ src_idx, const int* __restrict__ dst_idx,
    const unsigned short* __restrict__ nfb,
    const unsigned short* __restrict__ wall,
    const float* __restrict__ b1, const float* __restrict__ b2,
    const float* __restrict__ lns, const float* __restrict__ lnb,
    float* __restrict__ out)
{
  // [0, 49152)      : three 16KB W buffers
  // [49152, 51200)  : biases: b1 | b2 | ln_scale | ln_bias (128 f32 each)
  __shared__ __align__(16) unsigned char smem[51200];
  unsigned int* wbuf  = (unsigned int*)smem;
  float*        cmisc = (float*)(smem + 49152);

  const int tid  = threadIdx.x;
  const int w    = tid >> 6;
  const int lane = tid & 63;
  const int rl   = lane & 31;     // A row (chan) / B col (edge) / D col (edge)
  const int hi   = lane >> 5;     // k-half; D row-offset 4*hi
  const int swz  = (rl & 7) << 2; // dword XOR swizzle (b128-aligned)

  auto stageW = [&](int b, int win){
    const unsigned char* src = (const unsigned char*)wall + win * 16384;
    #pragma unroll
    for (int rnd = 0; rnd < 4; ++rnd){
      int off = rnd * 4096 + tid * 16;
      glds16(smem + b * 16384 + off, src + off);
    }
  };

  // prologue: first two windows + biases + per-edge indices + efeat prefetch
  stageW(0, 0);
  stageW(1, 1);
  cmisc[tid]       = tid < 128 ? b1[tid]  : b2[tid - 128];
  cmisc[tid + 256] = tid < 128 ? lns[tid] : lnb[tid - 128];

  const int e0 = blockIdx.x * 128 + w * 32 + rl;
  const int ec = e0 < E_N ? e0 : (E_N - 1);
  int si = src_idx[ec], di = dst_idx[ec];
  si = si < 0 ? 0 : (si >= N_N ? N_N - 1 : si);
  di = di < 0 ? 0 : (di >= N_N ? N_N - 1 : di);

  auto ldE = [&](int ks8) -> short8 {
    floatx8a f = *reinterpret_cast<const floatx8a*>(efeat + (size_t)ec * 128 + ks8 * 16 + hi * 8);
    return __builtin_bit_cast(short8, __builtin_convertvector(f, bf16x8));
  };

  short8 xe[8], ga[4], gb[4];
  #pragma unroll
  for (int ks8 = 0; ks8 < 8; ++ks8) xe[ks8] = ldE(ks8);

  auto gather4 = [&](short8* dst, int row, int k0){
    #pragma unroll
    for (int k = 0; k < 4; ++k)
      dst[k] = *reinterpret_cast<const short8a*>(nfb + (size_t)row * 128 + (k0 + k) * 16 + hi * 8);
  };

  // W A-frag: buffer b, m-tile m, kstep ks: row = 32m+rl, dwords (ks*8+hi*4)^swz
  auto loadW = [&](int b, int m, int ks) -> short8 {
    uintx4a v = *reinterpret_cast<const uintx4a*>(
        &wbuf[b * 4096 + (32 * m + rl) * 32 + ((ks * 8 + hi * 4) ^ swz)]);
    return __builtin_bit_cast(short8, v);
  };

  floatx16 acc1[4];
  #pragma unroll
  for (int mt = 0; mt < 4; ++mt)
    #pragma unroll
    for (int q = 0; q < 16; ++q) acc1[mt][q] = 0.f;

  auto g1win = [&](int b, const short8* xs){
    __builtin_amdgcn_s_setprio(1);
    #pragma unroll
    for (int ks = 0; ks < 4; ++ks){
      #pragma unroll
      for (int mt = 0; mt < 4; ++mt){
        short8 wf = loadW(b, mt, ks);
        acc1[mt] = __builtin_amdgcn_mfma_f32_32x32x16_bf16(wf, xs[ks], acc1[mt], 0, 0, 0);
      }
    }
    __builtin_amdgcn_s_setprio(0);
  };

  // ---- 8-phase counted-vmcnt pipeline -------------------------------------
  WAITBAR(0);                         // prologue drain (once)

  // t=0: win0 (buf0, xe[0..3]); prefetch stage win2 + gather(si lo)
  stageW(2, 2);
  g1win(0, xe);
  gather4(ga, si, 0);

  // t=1: win1 (buf1, xe[4..7]); prefetch stage win3 + gather(si hi)
  BARONLY();
  stageW(0, 3);
  g1win(1, xe + 4);
  gather4(gb, si, 4);

  // t=2: win2 (buf2, ga); prefetch stage win4 + gather(di lo)
  WAITBAR(8);
  stageW(1, 4);
  g1win(2, ga);
  gather4(ga, di, 0);

  // t=3: win3 (buf0, gb); prefetch stage win5 + gather(di hi)
  WAITBAR(8);
  stageW(2, 5);
  g1win(0, gb);
  gather4(gb, di, 4);

  // t=4: win4 (buf1, ga); prefetch stage win6
  WAITBAR(8);
  stageW(0, 6);
  g1win(1, ga);

  // t=5: win5 (buf2, gb); prefetch stage win7; then retire acc1 in registers
  WAITBAR(4);
  stageW(1, 7);
  g1win(2, gb);

  // ---- h-frag build IN REGISTERS: silu(acc1+b1) -> bf16 -> lane<->lane+32
  short8 hfr[8];
  #pragma unroll
  for (int mt = 0; mt < 4; ++mt){
    floatx4 sv[4];
    #pragma unroll
    for (int p = 0; p < 4; ++p){
      floatx4 bb = *reinterpret_cast<const floatx4a*>(&cmisc[32 * mt + 8 * p + 4 * hi]);
      #pragma unroll
      for (int i = 0; i < 4; ++i){
        float xx = acc1[mt][4 * p + i] + bb[i];
        sv[p][i] = xx * __builtin_amdgcn_rcpf(1.f + __expf(-xx));   // silu
      }
    }
    #pragma unroll
    for (int k1 = 0; k1 < 2; ++k1){
      uintx2 P0 = __builtin_bit_cast(uintx2, __builtin_convertvector(sv[2 * k1],     bf16x4));
      uintx2 P1 = __builtin_bit_cast(uintx2, __builtin_convertvector(sv[2 * k1 + 1], bf16x4));
      unsigned sA = hi ? P0[0] : P1[0];
      unsigned sB = hi ? P0[1] : P1[1];
      unsigned rA = __shfl_xor(sA, 32);
      unsigned rB = __shfl_xor(sB, 32);
      uintx4 u;
      u[0] = hi ? rA : P0[0];
      u[1] = hi ? rB : P0[1];
      u[2] = hi ? P1[0] : rA;
      u[3] = hi ? P1[1] : rB;
      hfr[2 * mt + k1] = __builtin_bit_cast(short8, u);
    }
  }

  // ---- residual exchange: xe frags -> (kept, received) half-packs
  uintx2 rk[8], rr[8];
  #pragma unroll
  for (int ks = 0; ks < 8; ++ks){
    uintx4 u = __builtin_bit_cast(uintx4, xe[ks]);
    unsigned sA = hi ? u[0] : u[2];
    unsigned sB = hi ? u[1] : u[3];
    rr[ks][0] = __shfl_xor(sA, 32);
    rr[ks][1] = __shfl_xor(sB, 32);
    rk[ks][0] = hi ? u[2] : u[0];
    rk[ks][1] = hi ? u[3] : u[1];
  }

  floatx16 acc2[4];
  #pragma unroll
  for (int mo = 0; mo < 4; ++mo)
    #pragma unroll
    for (int q = 0; q < 16; ++q) acc2[mo][q] = 0.f;

  // t=6: GEMM2 first half (buf0 = win6, hfr[0..3])
  WAITBAR(4);
  __builtin_amdgcn_s_setprio(1);
  #pragma unroll
  for (int ks = 0; ks < 4; ++ks)
    #pragma unroll
    for (int mo = 0; mo < 4; ++mo)
      acc2[mo] = __builtin_amdgcn_mfma_f32_32x32x16_bf16(loadW(0, mo, ks), hfr[ks], acc2[mo], 0, 0, 0);
  __builtin_amdgcn_s_setprio(0);

  // t=7: GEMM2 second half (buf1 = win7, hfr[4..7])
  WAITBAR(0);
  __builtin_amdgcn_s_setprio(1);
  #pragma unroll
  for (int ks = 0; ks < 4; ++ks)
    #pragma unroll
    for (int mo = 0; mo < 4; ++mo)
      acc2[mo] = __builtin_amdgcn_mfma_f32_32x32x16_bf16(loadW(1, mo, ks), hfr[4 + ks], acc2[mo], 0, 0, 0);
  __builtin_amdgcn_s_setprio(0);

  // ---- LN (1 shuffle pair), residual from rk/rr, float4 stores
  float s1 = 0.f, s2 = 0.f;
  #pragma unroll
  for (int mt = 0; mt < 4; ++mt)
    #pragma unroll
    for (int p = 0; p < 4; ++p){
      floatx4 bb = *reinterpret_cast<const floatx4a*>(&cmisc[128 + 32 * mt + 8 * p + 4 * hi]);
      #pragma unroll
      for (int i = 0; i < 4; ++i){
        float v = acc2[mt][4 * p + i] + bb[i];
        s1 += v; s2 += v * v;
      }
    }
  s1 += __shfl_xor(s1, 32); s2 += __shfl_xor(s2, 32);

  float mu   = s1 * (1.f / 128.f);
  float var  = s2 * (1.f / 128.f) - mu * mu;
  var = var > 0.f ? var : 0.f;
  float rstd = __builtin_amdgcn_rsqf(var + 1e-5f);

  if (e0 < E_N){
    float* op = out + (size_t)e0 * 128;
    #pragma unroll
    for (int mt = 0; mt < 4; ++mt)
      #pragma unroll
      for (int p = 0; p < 4; ++p){
        int c = 32 * mt + 8 * p + 4 * hi;
        floatx4 bb = *reinterpret_cast<const floatx4a*>(&cmisc[128 + c]);
        floatx4 ls = *reinterpret_cast<const floatx4a*>(&cmisc[256 + c]);
        floatx4 lb = *reinterpret_cast<const floatx4a*>(&cmisc[384 + c]);
        const int ks = 2 * mt + (p >> 1);
        uintx2 pk_ = ((p & 1) == hi) ? rk[ks] : rr[ks];
        floatx4 o4;
        #pragma unroll
        for (int i = 0; i < 4; ++i){
          unsigned dwv = pk_[i >> 1];
          float ef = __builtin_bit_cast(float, (i & 1) ? (dwv & 0xffff0000u) : (dwv << 16));
          o4[i] = (acc2[mt][4 * p + i] + bb[i] - mu) * rstd * ls[i] + lb[i] + ef;
        }
        *reinterpret_cast<floatx4a*>(op + c) = o4;
      }
  }
}

extern "C" void kernel_launch(void* const* d_in, const int* in_sizes, int n_in,
                              void* d_out, int out_size, void* d_ws, size_t ws_size,
                              hipStream_t stream){
  const float* efeat = (const float*)d_in[0];
  const float* nfeat = (const float*)d_in[1];
  const int*   srci  = (const int*)d_in[2];
  const int*   dsti  = (const int*)d_in[3];
  const float* W1    = (const float*)d_in[4];
  const float* b1    = (const float*)d_in[5];
  const float* W2    = (const float*)d_in[6];
  const float* b2    = (const float*)d_in[7];
  const float* lns   = (const float*)d_in[8];
  const float* lnb   = (const float*)d_in[9];
  float* out = (float*)d_out;

  char* ws = (char*)d_ws;
  unsigned short* wall = (unsigned short*)ws;              // 131,072 B (8 swizzled windows)
  unsigned short* nfb  = (unsigned short*)(ws + 131072);   // 25,600,000 B

  prep_weights<<<(384 * 128 + 128 * 128) / 256, 256, 0, stream>>>(W1, W2, wall);
  prep_nfeat<<<2048, 256, 0, stream>>>(nfeat, (unsigned*)nfb, out + (size_t)E_N * 128);

  int blocks = (E_N + 127) / 128;   // 4688
  fused_edge<<<blocks, 256, 0, stream>>>(efeat, srci, dsti, nfb, wall,
                                         b1, b2, lns, lnb, out);
}